// Round 1
// baseline (526.976 us; speedup 1.0000x reference)
//
#include <hip/hip_runtime.h>
#include <math.h>

#define CONF 0.25f
#define NCLS 80

// ---------------------------------------------------------------------------
// init: zero the completion-ticket counter (ws is poisoned between runs,
// so this must run every launch).
// ---------------------------------------------------------------------------
__global__ void yolo_init(unsigned int* __restrict__ done) {
    *done = 0u;
}

// ---------------------------------------------------------------------------
// fused: per-block (64 rows, 4 lanes/row) score pass producing
//   vrow[row]        = rowmax(logits) + sum4(boxes)         (per row, 1 MB)
//   chunksum[b]      = sum of vrow over this block's rows
//   chunkminfail[b]  = min row in chunk with score < CONF, else UINT_MAX
// then threadfence + ticket; the LAST block computes
//   j = min over chunks of chunkminfail   (global first failing row)
//   out = sum chunksum[c] for full chunks below j + boundary rows from vrow.
// Deterministic: reduction order is fixed regardless of which block is last.
// ---------------------------------------------------------------------------
__global__ __launch_bounds__(256) void yolo_fused(
    const float* __restrict__ logits,
    const float* __restrict__ boxes,
    float* __restrict__ vrow,
    float* __restrict__ chunksum,
    unsigned int* __restrict__ chunkminfail,
    unsigned int* __restrict__ done,
    float* __restrict__ out,
    unsigned int k, unsigned int nb)
{
    const int tid   = threadIdx.x;
    const int lane4 = tid & 3;
    const int grp   = tid >> 2;                         // 0..63 rows per block
    const unsigned int row = blockIdx.x * 64u + (unsigned int)grp;

    float v = 0.0f;                                     // score+boxsum, lane0 of group only
    unsigned int failrow = 0xFFFFFFFFu;

    if (row < k) {
        // 4 lanes per row read 20 float4 (320B contiguous, 64B-aligned segs)
        const float4* rp = (const float4*)(logits + (size_t)row * NCLS);
        float m = -INFINITY;
#pragma unroll
        for (int t = 0; t < 5; ++t) {
            float4 c4 = rp[lane4 + 4 * t];
            m = fmaxf(m, fmaxf(fmaxf(c4.x, c4.y), fmaxf(c4.z, c4.w)));
        }
        // reduce across the aligned 4-lane group
        m = fmaxf(m, __shfl_xor(m, 1));
        m = fmaxf(m, __shfl_xor(m, 2));

        if (lane4 == 0) {
            float4 b = ((const float4*)boxes)[row];
            v = m + (b.x + b.y) + (b.z + b.w);
            vrow[row] = v;
            if (m < CONF) failrow = row;                // essentially-never path
        }
    }

    // ---- per-wave reduce: sum of v (non-lane0 contribute 0), min failrow ----
    float ws_v = v;
    unsigned int wf = failrow;
#pragma unroll
    for (int o = 32; o > 0; o >>= 1) {
        ws_v += __shfl_down(ws_v, o);
        wf = min(wf, __shfl_down(wf, o));
    }

    __shared__ float        lsv[4];
    __shared__ unsigned int lsf[4];
    __shared__ unsigned int lsj[4];
    __shared__ int islast;

    const int lane = tid & 63;
    const int wid  = tid >> 6;
    if (lane == 0) { lsv[wid] = ws_v; lsf[wid] = wf; }
    __syncthreads();

    if (tid == 0) {
        float cs        = (lsv[0] + lsv[1]) + (lsv[2] + lsv[3]);
        unsigned int cf = min(min(lsf[0], lsf[1]), min(lsf[2], lsf[3]));
        chunksum[blockIdx.x]     = cs;
        chunkminfail[blockIdx.x] = cf;
        __threadfence();                                // release our stores
        unsigned int t = atomicAdd(done, 1u);           // device-scope
        islast = (t == nb - 1u);
    }
    __syncthreads();
    if (!islast) return;

    // ======================= last block: finish =======================
    __threadfence();                                    // acquire others' stores

    // 1) j = global first failing row = min over chunkminfail
    unsigned int jmin = 0xFFFFFFFFu;
    for (unsigned int c = (unsigned int)tid; c < nb; c += 256u)
        jmin = min(jmin, chunkminfail[c]);
#pragma unroll
    for (int o = 32; o > 0; o >>= 1) jmin = min(jmin, __shfl_down(jmin, o));
    if (lane == 0) lsj[wid] = jmin;
    __syncthreads();
    unsigned int j = min(min(lsj[0], lsj[1]), min(lsj[2], lsj[3]));
    if (j > k) j = k;

    // 2) sum of full chunks below j, plus boundary rows [cfull*64, j)
    const unsigned int cfull = j >> 6;
    float s = 0.0f;
    for (unsigned int c = (unsigned int)tid; c < cfull; c += 256u)
        s += chunksum[c];
    const unsigned int nbd = j & 63u;                   // boundary row count
    if ((unsigned int)tid < nbd)
        s += vrow[(size_t)cfull * 64u + (unsigned int)tid];

#pragma unroll
    for (int o = 32; o > 0; o >>= 1) s += __shfl_down(s, o);
    __syncthreads();                                    // lsv reuse safety
    if (lane == 0) lsv[wid] = s;
    __syncthreads();
    if (tid == 0) out[0] = (lsv[0] + lsv[1]) + (lsv[2] + lsv[3]);
}

extern "C" void kernel_launch(void* const* d_in, const int* in_sizes, int n_in,
                              void* d_out, int out_size, void* d_ws, size_t ws_size,
                              hipStream_t stream) {
    const float* logits = (const float*)d_in[0];
    const float* boxes  = (const float*)d_in[1];
    float* out = (float*)d_out;

    const unsigned int N = (unsigned int)(in_sizes[0] / NCLS);  // element counts
    unsigned int k = N / 4;                                     // RATIO = 0.25
    if (k < 1) k = 1;
    const unsigned int nb = (k + 63u) / 64u;

    // ws layout (256B-aligned sections):
    //   [0]    done counter (u32)
    //   [256]  chunkminfail (nb u32)
    //   [..]   chunksum     (nb f32)
    //   [..]   vrow         (k  f32)
    char* ws = (char*)d_ws;
    unsigned int* done = (unsigned int*)ws;
    size_t off = 256;
    unsigned int* cmf = (unsigned int*)(ws + off);
    off += ((size_t)nb * 4 + 255) & ~(size_t)255;
    float* csum = (float*)(ws + off);
    off += ((size_t)nb * 4 + 255) & ~(size_t)255;
    float* vrow = (float*)(ws + off);

    yolo_init<<<1, 1, 0, stream>>>(done);
    yolo_fused<<<nb, 256, 0, stream>>>(logits, boxes, vrow, csum, cmf, done, out, k, nb);
}

// Round 2
// 373.609 us; speedup vs baseline: 1.4105x; 1.4105x over previous
//
#include <hip/hip_runtime.h>
#include <math.h>

#define CONF 0.25f
#define NCLS 80

// ---------------------------------------------------------------------------
// Kernel 1: score pass. 64 rows/block, 4 lanes/row.
// Lanes of a 4-group read the row's 80 floats as 20 float4 (5 each,
// interleaved) -> 64B segments, full cache-line utilization.
// Writes per-row v = rowmax + sum4(box), per-chunk sum, per-chunk min-fail row.
// NO atomics, NO fences — cross-block visibility comes from the kernel
// boundary (runtime dispatch-packet release/acquire), which is one CP-side
// flush instead of 3907 per-block buffer_wbl2's (the round-1 mistake).
// ---------------------------------------------------------------------------
__global__ __launch_bounds__(256) void yolo_score(
    const float* __restrict__ logits,
    const float* __restrict__ boxes,
    float* __restrict__ vrow,
    float* __restrict__ chunksum,
    unsigned int* __restrict__ chunkminfail,
    unsigned int k)
{
    const int tid   = threadIdx.x;
    const int lane4 = tid & 3;
    const int grp   = tid >> 2;                         // 0..63 rows per block
    const unsigned int row = blockIdx.x * 64u + (unsigned int)grp;

    float v = 0.0f;                                     // lane0-of-group only
    unsigned int failrow = 0xFFFFFFFFu;

    if (row < k) {
        const float4* rp = (const float4*)(logits + (size_t)row * NCLS);
        float m = -INFINITY;
#pragma unroll
        for (int t = 0; t < 5; ++t) {
            float4 c4 = rp[lane4 + 4 * t];
            m = fmaxf(m, fmaxf(fmaxf(c4.x, c4.y), fmaxf(c4.z, c4.w)));
        }
        m = fmaxf(m, __shfl_xor(m, 1));
        m = fmaxf(m, __shfl_xor(m, 2));

        if (lane4 == 0) {
            float4 b = ((const float4*)boxes)[row];
            v = m + (b.x + b.y) + (b.z + b.w);
            vrow[row] = v;
            if (m < CONF) failrow = row;                // essentially-never
        }
    }

    // wave64 reduce: sum of v, min of failrow
    float sv = v;
    unsigned int wf = failrow;
#pragma unroll
    for (int o = 32; o > 0; o >>= 1) {
        sv += __shfl_down(sv, o);
        wf = min(wf, __shfl_down(wf, o));
    }

    __shared__ float        lsv[4];
    __shared__ unsigned int lsf[4];
    const int lane = tid & 63;
    const int wid  = tid >> 6;
    if (lane == 0) { lsv[wid] = sv; lsf[wid] = wf; }
    __syncthreads();
    if (tid == 0) {
        chunksum[blockIdx.x]     = (lsv[0] + lsv[1]) + (lsv[2] + lsv[3]);
        chunkminfail[blockIdx.x] = min(min(lsf[0], lsf[1]), min(lsf[2], lsf[3]));
    }
}

// ---------------------------------------------------------------------------
// Kernel 2: single-block finish. j = min over chunkminfail (global first
// failing row, clamped to k); out = sum of full chunks below j + boundary
// rows from vrow. Deterministic order -> bitwise-stable result.
// nb = 3907 -> 16 KB of chunk data: ~3 us including launch.
// ---------------------------------------------------------------------------
__global__ __launch_bounds__(256) void yolo_finish(
    const float* __restrict__ vrow,
    const float* __restrict__ chunksum,
    const unsigned int* __restrict__ chunkminfail,
    float* __restrict__ out,
    unsigned int k, unsigned int nb)
{
    const int tid  = threadIdx.x;
    const int lane = tid & 63;
    const int wid  = tid >> 6;

    __shared__ unsigned int lsj[4];
    __shared__ float        lsv[4];
    __shared__ unsigned int jsh;

    // 1) global first failing row
    unsigned int jmin = 0xFFFFFFFFu;
    for (unsigned int c = (unsigned int)tid; c < nb; c += 256u)
        jmin = min(jmin, chunkminfail[c]);
#pragma unroll
    for (int o = 32; o > 0; o >>= 1) jmin = min(jmin, __shfl_down(jmin, o));
    if (lane == 0) lsj[wid] = jmin;
    __syncthreads();
    if (tid == 0) {
        unsigned int j = min(min(lsj[0], lsj[1]), min(lsj[2], lsj[3]));
        jsh = (j > k) ? k : j;
    }
    __syncthreads();
    const unsigned int j = jsh;

    // 2) sum full chunks below j, plus boundary rows [cfull*64, j)
    const unsigned int cfull = j >> 6;
    float s = 0.0f;
    for (unsigned int c = (unsigned int)tid; c < cfull; c += 256u)
        s += chunksum[c];
    const unsigned int nbd = j & 63u;
    if ((unsigned int)tid < nbd)
        s += vrow[(size_t)cfull * 64u + (unsigned int)tid];

#pragma unroll
    for (int o = 32; o > 0; o >>= 1) s += __shfl_down(s, o);
    if (lane == 0) lsv[wid] = s;
    __syncthreads();
    if (tid == 0) out[0] = (lsv[0] + lsv[1]) + (lsv[2] + lsv[3]);
}

extern "C" void kernel_launch(void* const* d_in, const int* in_sizes, int n_in,
                              void* d_out, int out_size, void* d_ws, size_t ws_size,
                              hipStream_t stream) {
    const float* logits = (const float*)d_in[0];
    const float* boxes  = (const float*)d_in[1];
    float* out = (float*)d_out;

    const unsigned int N = (unsigned int)(in_sizes[0] / NCLS);
    unsigned int k = N / 4;                              // RATIO = 0.25
    if (k < 1) k = 1;
    const unsigned int nb = (k + 63u) / 64u;

    // ws layout (256B-aligned sections):
    //   [0]   chunkminfail (nb u32)   — written in full by kernel 1
    //   [..]  chunksum     (nb f32)   — written in full by kernel 1
    //   [..]  vrow         (k  f32)   — rows < k written by kernel 1
    char* ws = (char*)d_ws;
    size_t off = 0;
    unsigned int* cmf = (unsigned int*)(ws + off);
    off += ((size_t)nb * 4 + 255) & ~(size_t)255;
    float* csum = (float*)(ws + off);
    off += ((size_t)nb * 4 + 255) & ~(size_t)255;
    float* vrow = (float*)(ws + off);

    yolo_score<<<nb, 256, 0, stream>>>(logits, boxes, vrow, csum, cmf, k);
    yolo_finish<<<1, 256, 0, stream>>>(vrow, csum, cmf, out, k, nb);
}

// Round 3
// 368.476 us; speedup vs baseline: 1.4302x; 1.0139x over previous
//
#include <hip/hip_runtime.h>
#include <math.h>

#define CONF 0.25f
#define NCLS 80

// ---------------------------------------------------------------------------
// Kernel 1: score pass. 256 rows/block (1024 threads), 4 lanes/row.
// All 5 logits float4 loads + the box load are issued into NAMED registers
// before any consumption: round-1's VGPR_Count=16 proved the compiler was
// serializing load->vmcnt(0)->fmax (VALUBusy 1.3% = ~1% duty cycle). This
// forces ~28-32 VGPRs and 5x the memory-level parallelism per lane.
// Boxes are read one float per lane of the 4-group (wave reads 256B
// contiguous) instead of a divergent lane0 float4: 4 MB instead of 16 MB.
// Emits per-row v = rowmax+boxsum, per-chunk sum, per-chunk min failing row.
// No atomics, no fences (round-1 lesson: per-block device fences = 197 us).
// ---------------------------------------------------------------------------
__global__ __launch_bounds__(1024) void yolo_score(
    const float* __restrict__ logits,
    const float* __restrict__ boxes,
    float* __restrict__ vrow,
    float* __restrict__ chunksum,
    unsigned int* __restrict__ chunkminfail,
    unsigned int k)
{
    const int tid   = threadIdx.x;
    const int lane4 = tid & 3;
    const int grp   = tid >> 2;                         // 0..255 rows/block
    const unsigned int row = blockIdx.x * 256u + (unsigned int)grp;

    float v = 0.0f;                                     // lane0-of-group only
    unsigned int failrow = 0xFFFFFFFFu;

    if (row < k) {
        const float4* rp = (const float4*)(logits + (size_t)row * NCLS);
        // ---- issue all 6 loads back-to-back (no dependent use between) ----
        float4 c0 = rp[lane4 +  0];
        float4 c1 = rp[lane4 +  4];
        float4 c2 = rp[lane4 +  8];
        float4 c3 = rp[lane4 + 12];
        float4 c4 = rp[lane4 + 16];
        float  bx = boxes[4u * row + (unsigned int)lane4];

        float m0 = fmaxf(fmaxf(c0.x, c0.y), fmaxf(c0.z, c0.w));
        float m1 = fmaxf(fmaxf(c1.x, c1.y), fmaxf(c1.z, c1.w));
        float m2 = fmaxf(fmaxf(c2.x, c2.y), fmaxf(c2.z, c2.w));
        float m3 = fmaxf(fmaxf(c3.x, c3.y), fmaxf(c3.z, c3.w));
        float m4 = fmaxf(fmaxf(c4.x, c4.y), fmaxf(c4.z, c4.w));
        float m  = fmaxf(fmaxf(fmaxf(m0, m1), fmaxf(m2, m3)), m4);

        // aligned 4-lane group reduce: max(m), sum(bx)
        m  = fmaxf(m, __shfl_xor(m, 1));
        m  = fmaxf(m, __shfl_xor(m, 2));
        bx += __shfl_xor(bx, 1);
        bx += __shfl_xor(bx, 2);

        if (lane4 == 0) {
            v = m + bx;
            vrow[row] = v;
            if (m < CONF) failrow = row;                // essentially-never
        }
    }

    // wave64 reduce: sum of v, min of failrow
    float sv = v;
    unsigned int wf = failrow;
#pragma unroll
    for (int o = 32; o > 0; o >>= 1) {
        sv += __shfl_down(sv, o);
        wf = min(wf, __shfl_down(wf, o));
    }

    __shared__ float        lsv[16];
    __shared__ unsigned int lsf[16];
    const int lane = tid & 63;
    const int wid  = tid >> 6;
    if (lane == 0) { lsv[wid] = sv; lsf[wid] = wf; }
    __syncthreads();
    if (tid == 0) {
        float cs = 0.0f;
        unsigned int cf = 0xFFFFFFFFu;
#pragma unroll
        for (int w = 0; w < 16; ++w) { cs += lsv[w]; cf = min(cf, lsf[w]); }
        chunksum[blockIdx.x]     = cs;
        chunkminfail[blockIdx.x] = cf;
    }
}

// ---------------------------------------------------------------------------
// Kernel 2: single-block finish, 1024 threads. nb = ceil(k/256) = 977, so
// each chunk array is read in ONE fully-parallel round (the old 256-thread
// version did 16+16 serialized latency-bound rounds over L3).
// j = min(chunkminfail) clamped to k; out = full chunks below j + boundary
// rows from vrow. Fixed reduction order -> bitwise-deterministic.
// ---------------------------------------------------------------------------
__global__ __launch_bounds__(1024) void yolo_finish(
    const float* __restrict__ vrow,
    const float* __restrict__ chunksum,
    const unsigned int* __restrict__ chunkminfail,
    float* __restrict__ out,
    unsigned int k, unsigned int nb)
{
    const int tid  = threadIdx.x;
    const int lane = tid & 63;
    const int wid  = tid >> 6;

    __shared__ unsigned int lsj[16];
    __shared__ float        lsv[16];
    __shared__ unsigned int jsh;

    // 1) global first failing row
    unsigned int jmin = 0xFFFFFFFFu;
    for (unsigned int c = (unsigned int)tid; c < nb; c += 1024u)
        jmin = min(jmin, chunkminfail[c]);
#pragma unroll
    for (int o = 32; o > 0; o >>= 1) jmin = min(jmin, __shfl_down(jmin, o));
    if (lane == 0) lsj[wid] = jmin;
    __syncthreads();
    if (tid == 0) {
        unsigned int j = 0xFFFFFFFFu;
#pragma unroll
        for (int w = 0; w < 16; ++w) j = min(j, lsj[w]);
        jsh = (j > k) ? k : j;
    }
    __syncthreads();
    const unsigned int j = jsh;

    // 2) sum full chunks below j, plus boundary rows [cfull*256, j)
    const unsigned int cfull = j >> 8;                  // 256 rows per chunk
    float s = 0.0f;
    for (unsigned int c = (unsigned int)tid; c < cfull; c += 1024u)
        s += chunksum[c];
    const unsigned int nbd = j & 255u;
    if ((unsigned int)tid < nbd)
        s += vrow[(size_t)cfull * 256u + (unsigned int)tid];

#pragma unroll
    for (int o = 32; o > 0; o >>= 1) s += __shfl_down(s, o);
    if (lane == 0) lsv[wid] = s;
    __syncthreads();
    if (tid == 0) {
        float t = 0.0f;
#pragma unroll
        for (int w = 0; w < 16; ++w) t += lsv[w];
        out[0] = t;
    }
}

extern "C" void kernel_launch(void* const* d_in, const int* in_sizes, int n_in,
                              void* d_out, int out_size, void* d_ws, size_t ws_size,
                              hipStream_t stream) {
    const float* logits = (const float*)d_in[0];
    const float* boxes  = (const float*)d_in[1];
    float* out = (float*)d_out;

    const unsigned int N = (unsigned int)(in_sizes[0] / NCLS);
    unsigned int k = N / 4;                              // RATIO = 0.25
    if (k < 1) k = 1;
    const unsigned int nb = (k + 255u) / 256u;           // 256 rows per chunk

    // ws layout (256B-aligned sections):
    //   [0]   chunkminfail (nb u32)
    //   [..]  chunksum     (nb f32)
    //   [..]  vrow         (k  f32)
    char* ws = (char*)d_ws;
    size_t off = 0;
    unsigned int* cmf = (unsigned int*)(ws + off);
    off += ((size_t)nb * 4 + 255) & ~(size_t)255;
    float* csum = (float*)(ws + off);
    off += ((size_t)nb * 4 + 255) & ~(size_t)255;
    float* vrow = (float*)(ws + off);

    yolo_score<<<nb, 1024, 0, stream>>>(logits, boxes, vrow, csum, cmf, k);
    yolo_finish<<<1, 1024, 0, stream>>>(vrow, csum, cmf, out, k, nb);
}